// Round 3
// baseline (148.839 us; speedup 1.0000x reference)
//
#include <hip/hip_runtime.h>
#include <hip/hip_bf16.h>
#include <stdint.h>

// Problem constants
#define BB   32
#define LL   4096
#define CCH  64
#define NPp  256
#define DOUT 512
#define DINX 1024            // x-part only: PL*PC (t-part folded analytically)
#define MM   (BB * NPp)      // 8192 patch-rows
#define TT   0.001f          // 1/FS

using bf16 = __hip_bfloat16;
typedef __attribute__((ext_vector_type(8))) short bf16x8;
typedef __attribute__((ext_vector_type(4))) float f32x4;

__device__ __forceinline__ void async_copy16(void* lds, const void* g) {
    __builtin_amdgcn_global_load_lds(
        (const __attribute__((address_space(1))) void*)g,
        (__attribute__((address_space(3))) void*)lds,
        16, 0, 0);
}

__device__ __forceinline__ uint2 pack4_bf16(float a, float b, float c, float d) {
    union { bf16 h[4]; uint2 u; } p;
    p.h[0] = __float2bfloat16(a);
    p.h[1] = __float2bfloat16(b);
    p.h[2] = __float2bfloat16(c);
    p.h[3] = __float2bfloat16(d);
    return p.u;
}

// ---------------------------------------------------------------------------
// Fused prep (one launch):
//   blocks [0,512):   w1x[o][l*16+j] = bf16(w1[o][l*32+j])       512x1024
//   blocks [512,768): w2b = bf16(w2)                              512x512
//   blocks [768,896): affine terms  A1[o] = T*sum_l W1t[o][l],
//                     C1[o] = b1[o] + T*sum_l l*W1t[o][l],
//                     W1t[o][l] = sum_{j<16} w1[o][l*32+16+j]     (1 wave/o)
// ---------------------------------------------------------------------------
__global__ __launch_bounds__(256) void prep(
    const float* __restrict__ w1, const float* __restrict__ b1,
    const float* __restrict__ w2,
    bf16* __restrict__ w1x, bf16* __restrict__ w2b,
    float* __restrict__ A1, float* __restrict__ C1)
{
    const int blk = blockIdx.x;
    if (blk < 512) {
        int i = (blk * 256 + threadIdx.x) * 4;          // over 512*1024
        int o = i >> 10, r = i & 1023;
        int l = r >> 4, j = r & 15;
        float4 v = *(const float4*)(w1 + (size_t)o * 2048 + l * 32 + j);
        *(uint2*)(w1x + i) = pack4_bf16(v.x, v.y, v.z, v.w);
    } else if (blk < 768) {
        int i = ((blk - 512) * 256 + threadIdx.x) * 4;  // over 512*512
        float4 v = *(const float4*)(w2 + i);
        *(uint2*)(w2b + i) = pack4_bf16(v.x, v.y, v.z, v.w);
    } else {
        const int o = (blk - 768) * 4 + (threadIdx.x >> 6);
        const int l = threadIdx.x & 63;
        const float* wr = w1 + (size_t)o * 2048 + l * 32 + 16;
        float s0 = 0.f;
#pragma unroll
        for (int j = 0; j < 16; ++j) s0 += wr[j];
        float s1 = (float)l * s0;
#pragma unroll
        for (int off = 32; off > 0; off >>= 1) {
            s0 += __shfl_down(s0, off);
            s1 += __shfl_down(s1, off);
        }
        if (l == 0) {
            A1[o] = TT * s0;
            C1[o] = b1[o] + TT * s1;
        }
    }
}

// ---------------------------------------------------------------------------
// GEMM1 with fused gather:
//   h[m][o] = silu( sum_k feats[m][k]*w1x[o][k] + sL[m]*A1[o] + C1[o] )
//   feats[m][l*16+j] = x[b, sL[m]+l, sC[m]+j]  (gathered in-staging, bf16)
// 64x64 tile, BK=64 (16 iters), 4 waves -> 2x2 MFMA sub-tiles.
// A-tile LDS padded to stride 72 (write pattern hits all 32 banks, reads stay
// 16B-aligned: 72*2=144 = 9*16). B staged via global_load_lds x16.
// ---------------------------------------------------------------------------
__global__ __launch_bounds__(256, 4) void gemm1_fused(
    const float* __restrict__ x, const int* __restrict__ sL,
    const int* __restrict__ sC, const bf16* __restrict__ w1x,
    const float* __restrict__ A1, const float* __restrict__ C1,
    bf16* __restrict__ h)
{
    constexpr int BK = 64;
    constexpr int ASTR = 72;
    __shared__ __align__(16) bf16 As[64 * ASTR];
    __shared__ __align__(16) bf16 Bs[64 * BK];

    const int tid  = threadIdx.x;
    const int lane = tid & 63;
    const int wave = tid >> 6;
    const int row0 = blockIdx.x * 64;
    const int col0 = blockIdx.y * 64;
    const int b    = row0 >> 8;            // 64-row block lies in one batch

    // Gather assignment: thread -> (patch grow, l-segment gseg)
    const int grow = tid >> 2;             // 0..63
    const int gseg = tid & 3;              // l = l0 + gseg
    const int gsl  = sL[row0 + grow];
    const int gsc  = sC[row0 + grow];
    const float* xb = x + (size_t)b * LL * CCH + gsc;
    bf16* ad = &As[grow * ASTR + gseg * 16];

    // B staging: wave stages rows [wave*16, wave*16+16), 2 asyncs of 1KB
    const int  brow  = wave * 16 + (lane >> 3);
    const int  bkoff = (lane & 7) * 8;
    const bf16* bgp = w1x + (size_t)(col0 + brow) * DINX + bkoff;
    bf16* bs0 = &Bs[(wave * 16 + 0) * BK];
    bf16* bs1 = &Bs[(wave * 16 + 8) * BK];

    const int mw = (wave >> 1) * 32;
    const int nw = (wave & 1) * 32;
    const int fr = lane & 15;
    const int fq = lane >> 4;

    f32x4 acc[2][2] = {};

    for (int k0 = 0, l0 = 0; k0 < DINX; k0 += BK, l0 += 4) {
        // A gather loads (into regs; overlap with barrier)
        const float* src = xb + (size_t)(gsl + l0 + gseg) * CCH;
        float4 v0 = *(const float4*)(src);
        float4 v1 = *(const float4*)(src + 4);
        float4 v2 = *(const float4*)(src + 8);
        float4 v3 = *(const float4*)(src + 12);

        __syncthreads();                    // prev iter's frag reads done
        async_copy16(bs0, bgp + k0);
        async_copy16(bs1, bgp + (size_t)8 * DINX + k0);
        uint4 pk0, pk1;
        uint2 a01 = pack4_bf16(v0.x, v0.y, v0.z, v0.w);
        uint2 a23 = pack4_bf16(v1.x, v1.y, v1.z, v1.w);
        pk0.x = a01.x; pk0.y = a01.y; pk0.z = a23.x; pk0.w = a23.y;
        a01 = pack4_bf16(v2.x, v2.y, v2.z, v2.w);
        a23 = pack4_bf16(v3.x, v3.y, v3.z, v3.w);
        pk1.x = a01.x; pk1.y = a01.y; pk1.z = a23.x; pk1.w = a23.y;
        *(uint4*)(ad)     = pk0;
        *(uint4*)(ad + 8) = pk1;
        __syncthreads();                    // staging (async + ds_write) done

        bf16x8 af[2][2], bfr[2][2];
#pragma unroll
        for (int i = 0; i < 2; ++i)
#pragma unroll
            for (int ks = 0; ks < 2; ++ks)
                af[i][ks] = *(const bf16x8*)&As[(mw + i * 16 + fr) * ASTR + ks * 32 + fq * 8];
#pragma unroll
        for (int j = 0; j < 2; ++j)
#pragma unroll
            for (int ks = 0; ks < 2; ++ks)
                bfr[j][ks] = *(const bf16x8*)&Bs[(nw + j * 16 + fr) * BK + ks * 32 + fq * 8];
#pragma unroll
        for (int ks = 0; ks < 2; ++ks)
#pragma unroll
            for (int i = 0; i < 2; ++i)
#pragma unroll
                for (int j = 0; j < 2; ++j)
                    acc[i][j] = __builtin_amdgcn_mfma_f32_16x16x32_bf16(
                        af[i][ks], bfr[j][ks], acc[i][j], 0, 0, 0);
    }

    // Epilogue: + sL*A1 + C1, silu, bf16
    float slr[2][4];
#pragma unroll
    for (int i = 0; i < 2; ++i)
#pragma unroll
        for (int r = 0; r < 4; ++r)
            slr[i][r] = (float)sL[row0 + mw + i * 16 + fq * 4 + r];
#pragma unroll
    for (int j = 0; j < 2; ++j) {
        const int col = col0 + nw + j * 16 + fr;
        const float av = A1[col];
        const float cv = C1[col];
#pragma unroll
        for (int i = 0; i < 2; ++i)
#pragma unroll
            for (int r = 0; r < 4; ++r) {
                const int row = row0 + mw + i * 16 + fq * 4 + r;
                float v = acc[i][j][r] + slr[i][r] * av + cv;
                v = v / (1.0f + __expf(-v));
                h[(size_t)row * DOUT + col] = __float2bfloat16(v);
            }
    }
}

// ---------------------------------------------------------------------------
// GEMM2: out[m][q] = sum_o h[m][o]*w2b[q][o] + b2[q]   (fp32 out)
// 64x64 tile, BK=64 (8 iters), both operands via global_load_lds x16.
// ---------------------------------------------------------------------------
__global__ __launch_bounds__(256, 4) void gemm2(
    const bf16* __restrict__ A,   // h: M x 512
    const bf16* __restrict__ Bt,  // w2b: 512 x 512
    const float* __restrict__ bias,
    float* __restrict__ out)
{
    constexpr int BK = 64;
    constexpr int K  = DOUT;
    __shared__ __align__(16) bf16 As[64 * BK];
    __shared__ __align__(16) bf16 Bs[64 * BK];

    const int tid  = threadIdx.x;
    const int lane = tid & 63;
    const int wave = tid >> 6;
    const int row0 = blockIdx.x * 64;
    const int col0 = blockIdx.y * 64;

    const int  srow  = wave * 16 + (lane >> 3);
    const int  skoff = (lane & 7) * 8;
    const bf16* agp = A  + (size_t)(row0 + srow) * K + skoff;
    const bf16* bgp = Bt + (size_t)(col0 + srow) * K + skoff;
    bf16* as0 = &As[(wave * 16 + 0) * BK];
    bf16* as1 = &As[(wave * 16 + 8) * BK];
    bf16* bs0 = &Bs[(wave * 16 + 0) * BK];
    bf16* bs1 = &Bs[(wave * 16 + 8) * BK];

    const int mw = (wave >> 1) * 32;
    const int nw = (wave & 1) * 32;
    const int fr = lane & 15;
    const int fq = lane >> 4;

    f32x4 acc[2][2] = {};

    for (int k0 = 0; k0 < K; k0 += BK) {
        __syncthreads();
        async_copy16(as0, agp + k0);
        async_copy16(as1, agp + (size_t)8 * K + k0);
        async_copy16(bs0, bgp + k0);
        async_copy16(bs1, bgp + (size_t)8 * K + k0);
        __syncthreads();

        bf16x8 af[2][2], bfr[2][2];
#pragma unroll
        for (int i = 0; i < 2; ++i)
#pragma unroll
            for (int ks = 0; ks < 2; ++ks)
                af[i][ks] = *(const bf16x8*)&As[(mw + i * 16 + fr) * BK + ks * 32 + fq * 8];
#pragma unroll
        for (int j = 0; j < 2; ++j)
#pragma unroll
            for (int ks = 0; ks < 2; ++ks)
                bfr[j][ks] = *(const bf16x8*)&Bs[(nw + j * 16 + fr) * BK + ks * 32 + fq * 8];
#pragma unroll
        for (int ks = 0; ks < 2; ++ks)
#pragma unroll
            for (int i = 0; i < 2; ++i)
#pragma unroll
                for (int j = 0; j < 2; ++j)
                    acc[i][j] = __builtin_amdgcn_mfma_f32_16x16x32_bf16(
                        af[i][ks], bfr[j][ks], acc[i][j], 0, 0, 0);
    }

#pragma unroll
    for (int j = 0; j < 2; ++j) {
        const int col = col0 + nw + j * 16 + fr;
        const float bv = bias[col];
#pragma unroll
        for (int i = 0; i < 2; ++i)
#pragma unroll
            for (int r = 0; r < 4; ++r) {
                const int row = row0 + mw + i * 16 + fq * 4 + r;
                out[(size_t)row * DOUT + col] = acc[i][j][r] + bv;
            }
    }
}

// ---------------------------------------------------------------------------
extern "C" void kernel_launch(void* const* d_in, const int* in_sizes, int n_in,
                              void* d_out, int out_size, void* d_ws, size_t ws_size,
                              hipStream_t stream)
{
    const float* x  = (const float*)d_in[0];
    const int*   sL = (const int*)  d_in[1];
    const int*   sC = (const int*)  d_in[2];
    const float* w1 = (const float*)d_in[3];
    const float* b1 = (const float*)d_in[4];
    const float* w2 = (const float*)d_in[5];
    const float* b2 = (const float*)d_in[6];
    float* out = (float*)d_out;

    char* ws = (char*)d_ws;
    bf16* w1x = (bf16*)ws;                         size_t off = (size_t)DOUT * DINX * 2;
    bf16* w2b = (bf16*)(ws + off);                 off += (size_t)DOUT * DOUT * 2;
    bf16* hB  = (bf16*)(ws + off);                 off += (size_t)MM * DOUT * 2;
    float* A1 = (float*)(ws + off);                off += DOUT * 4;
    float* C1 = (float*)(ws + off);

    prep<<<896, 256, 0, stream>>>(w1, b1, w2, w1x, w2b, A1, C1);

    gemm1_fused<<<dim3(MM / 64, DOUT / 64), 256, 0, stream>>>(
        x, sL, sC, w1x, A1, C1, hB);

    gemm2<<<dim3(MM / 64, DOUT / 64), 256, 0, stream>>>(
        hB, w2b, b2, out);
}

// Round 4
// 134.196 us; speedup vs baseline: 1.1091x; 1.1091x over previous
//
#include <hip/hip_runtime.h>
#include <hip/hip_bf16.h>
#include <stdint.h>

// Problem constants
#define BB   32
#define LL   4096
#define CCH  64
#define NPp  256
#define DOUT 512
#define DINX 1024            // x-part only: PL*PC (t-part folded analytically)
#define MM   (BB * NPp)      // 8192 patch-rows
#define TT   0.001f          // 1/FS

using bf16 = __hip_bfloat16;
typedef __attribute__((ext_vector_type(8))) short bf16x8;
typedef __attribute__((ext_vector_type(4))) float f32x4;

__device__ __forceinline__ void async_copy16(void* lds, const void* g) {
    __builtin_amdgcn_global_load_lds(
        (const __attribute__((address_space(1))) void*)g,
        (__attribute__((address_space(3))) void*)lds,
        16, 0, 0);
}

__device__ __forceinline__ uint2 pack4_bf16(float a, float b, float c, float d) {
    union { bf16 h[4]; uint2 u; } p;
    p.h[0] = __float2bfloat16(a);
    p.h[1] = __float2bfloat16(b);
    p.h[2] = __float2bfloat16(c);
    p.h[3] = __float2bfloat16(d);
    return p.u;
}

// ---------------------------------------------------------------------------
// Fused prep (one launch):
//   blocks [0,512):   w1x[o][l*16+j] = bf16(w1[o][l*32+j])       512x1024
//   blocks [512,768): w2b = bf16(w2)                              512x512
//   blocks [768,896): A1[o] = T*sum_l W1t[o][l]
//                     C1[o] = b1[o] + T*sum_l l*W1t[o][l]
//                     W1t[o][l] = sum_{j<16} w1[o][l*32+16+j]     (1 wave/o)
// ---------------------------------------------------------------------------
__global__ __launch_bounds__(256) void prep(
    const float* __restrict__ w1, const float* __restrict__ b1,
    const float* __restrict__ w2,
    bf16* __restrict__ w1x, bf16* __restrict__ w2b,
    float* __restrict__ A1, float* __restrict__ C1)
{
    const int blk = blockIdx.x;
    if (blk < 512) {
        int i = (blk * 256 + threadIdx.x) * 4;
        int o = i >> 10, r = i & 1023;
        int l = r >> 4, j = r & 15;
        float4 v = *(const float4*)(w1 + (size_t)o * 2048 + l * 32 + j);
        *(uint2*)(w1x + i) = pack4_bf16(v.x, v.y, v.z, v.w);
    } else if (blk < 768) {
        int i = ((blk - 512) * 256 + threadIdx.x) * 4;
        float4 v = *(const float4*)(w2 + i);
        *(uint2*)(w2b + i) = pack4_bf16(v.x, v.y, v.z, v.w);
    } else {
        const int o = (blk - 768) * 4 + (threadIdx.x >> 6);
        const int l = threadIdx.x & 63;
        const float* wr = w1 + (size_t)o * 2048 + l * 32 + 16;
        float s0 = 0.f;
#pragma unroll
        for (int j = 0; j < 16; ++j) s0 += wr[j];
        float s1 = (float)l * s0;
#pragma unroll
        for (int off = 32; off > 0; off >>= 1) {
            s0 += __shfl_down(s0, off);
            s1 += __shfl_down(s1, off);
        }
        if (l == 0) {
            A1[o] = TT * s0;
            C1[o] = b1[o] + TT * s1;
        }
    }
}

// ---------------------------------------------------------------------------
// Gather (split, massively parallel): feats[m][l*16+j] = x[b, sL+l, sC+j]
// 4 patches/block, lane = l. 64 B/lane contiguous fp32 read, 32 B/lane
// coalesced bf16 write.
// ---------------------------------------------------------------------------
__global__ __launch_bounds__(256) void gather_feats(
    const float* __restrict__ x, const int* __restrict__ startL,
    const int* __restrict__ startC, bf16* __restrict__ feats)
{
    const int m = blockIdx.x * 4 + (threadIdx.x >> 6);
    const int b = m >> 8;
    const int l = threadIdx.x & 63;
    const int sl = startL[m];
    const int sc = startC[m];
    const float* src = x + ((size_t)b * LL + (size_t)(sl + l)) * CCH + sc;
    float4 v0 = *(const float4*)(src);
    float4 v1 = *(const float4*)(src + 4);
    float4 v2 = *(const float4*)(src + 8);
    float4 v3 = *(const float4*)(src + 12);
    uint4 p0, p1;
    uint2 a = pack4_bf16(v0.x, v0.y, v0.z, v0.w);
    uint2 c = pack4_bf16(v1.x, v1.y, v1.z, v1.w);
    p0.x = a.x; p0.y = a.y; p0.z = c.x; p0.w = c.y;
    a = pack4_bf16(v2.x, v2.y, v2.z, v2.w);
    c = pack4_bf16(v3.x, v3.y, v3.z, v3.w);
    p1.x = a.x; p1.y = a.y; p1.z = c.x; p1.w = c.y;
    bf16* dst = feats + (size_t)m * DINX + l * 16;
    *(uint4*)dst       = p0;
    *(uint4*)(dst + 8) = p1;
}

// ---------------------------------------------------------------------------
// Double-buffered GEMM: C[m][n] = act(sum_k A[m][k]*Bt[n][k] + ...)
// 64x64 tile, BK=64, 4 waves -> 32x32 each (2x2 MFMA frags x 2 k-halves).
// One __syncthreads per iter; tile k+1 prefetched via global_load_lds right
// after the barrier so the next barrier's vmcnt(0) drain overlaps compute.
// FUSE1: out bf16 = silu(acc + sL[row]*A1[col] + C1[col]); else fp32 acc+bias.
// ---------------------------------------------------------------------------
template <bool FUSE1>
__global__ __launch_bounds__(256, 4) void gemm_db(
    const bf16* __restrict__ A,   // M x K row-major
    const bf16* __restrict__ Bt,  // N x K row-major
    const float* __restrict__ P1,     // FUSE1: A1 ; else bias
    const float* __restrict__ C1,     // FUSE1 only
    const int*   __restrict__ sL,     // FUSE1 only
    void* __restrict__ outp,
    const int N, const int K)
{
    constexpr int BK = 64;
    __shared__ __align__(16) bf16 As[2][64 * BK];
    __shared__ __align__(16) bf16 Bs[2][64 * BK];

    const int tid  = threadIdx.x;
    const int lane = tid & 63;
    const int wave = tid >> 6;
    const int row0 = blockIdx.x * 64;
    const int col0 = blockIdx.y * 64;

    // Staging: wave stages 16 rows of A and B (2 asyncs each of 8 rows).
    const int  srow  = wave * 16 + (lane >> 3);
    const int  skoff = (lane & 7) * 8;
    const bf16* agp = A  + (size_t)(row0 + srow) * K + skoff;
    const bf16* bgp = Bt + (size_t)(col0 + srow) * K + skoff;
    const int w16 = wave * 16;

    const int mw = (wave >> 1) * 32;
    const int nw = (wave & 1) * 32;
    const int fr = lane & 15;
    const int fq = lane >> 4;

    f32x4 acc[2][2] = {};

    const int nIter = K / BK;

    // Preload tile 0
    async_copy16(&As[0][(w16 + 0) * BK], agp);
    async_copy16(&As[0][(w16 + 8) * BK], agp + (size_t)8 * K);
    async_copy16(&Bs[0][(w16 + 0) * BK], bgp);
    async_copy16(&Bs[0][(w16 + 8) * BK], bgp + (size_t)8 * K);

    for (int it = 0; it < nIter; ++it) {
        __syncthreads();   // drains vmcnt -> buf[it&1] ready; prev reads done
        const int cur = it & 1;
        if (it + 1 < nIter) {
            const int nxt = cur ^ 1;
            const int k1 = (it + 1) * BK;
            async_copy16(&As[nxt][(w16 + 0) * BK], agp + k1);
            async_copy16(&As[nxt][(w16 + 8) * BK], agp + (size_t)8 * K + k1);
            async_copy16(&Bs[nxt][(w16 + 0) * BK], bgp + k1);
            async_copy16(&Bs[nxt][(w16 + 8) * BK], bgp + (size_t)8 * K + k1);
        }

        bf16x8 af[2][2], bfr[2][2];
#pragma unroll
        for (int i = 0; i < 2; ++i)
#pragma unroll
            for (int ks = 0; ks < 2; ++ks)
                af[i][ks] = *(const bf16x8*)&As[cur][(mw + i * 16 + fr) * BK + ks * 32 + fq * 8];
#pragma unroll
        for (int j = 0; j < 2; ++j)
#pragma unroll
            for (int ks = 0; ks < 2; ++ks)
                bfr[j][ks] = *(const bf16x8*)&Bs[cur][(nw + j * 16 + fr) * BK + ks * 32 + fq * 8];
#pragma unroll
        for (int ks = 0; ks < 2; ++ks)
#pragma unroll
            for (int i = 0; i < 2; ++i)
#pragma unroll
                for (int j = 0; j < 2; ++j)
                    acc[i][j] = __builtin_amdgcn_mfma_f32_16x16x32_bf16(
                        af[i][ks], bfr[j][ks], acc[i][j], 0, 0, 0);
    }

    // Epilogue. C/D mapping: col = lane&15, row = (lane>>4)*4 + r
    float slr[2][4];
    if (FUSE1) {
#pragma unroll
        for (int i = 0; i < 2; ++i)
#pragma unroll
            for (int r = 0; r < 4; ++r)
                slr[i][r] = (float)sL[row0 + mw + i * 16 + fq * 4 + r];
    }
#pragma unroll
    for (int j = 0; j < 2; ++j) {
        const int col = col0 + nw + j * 16 + fr;
        const float bv = P1[col];
        const float cv = FUSE1 ? C1[col] : 0.f;
#pragma unroll
        for (int i = 0; i < 2; ++i)
#pragma unroll
            for (int r = 0; r < 4; ++r) {
                const int row = row0 + mw + i * 16 + fq * 4 + r;
                if (FUSE1) {
                    float v = acc[i][j][r] + slr[i][r] * bv + cv;
                    v = v / (1.0f + __expf(-v));
                    ((bf16*)outp)[(size_t)row * N + col] = __float2bfloat16(v);
                } else {
                    ((float*)outp)[(size_t)row * N + col] = acc[i][j][r] + bv;
                }
            }
    }
}

// ---------------------------------------------------------------------------
extern "C" void kernel_launch(void* const* d_in, const int* in_sizes, int n_in,
                              void* d_out, int out_size, void* d_ws, size_t ws_size,
                              hipStream_t stream)
{
    const float* x  = (const float*)d_in[0];
    const int*   sL = (const int*)  d_in[1];
    const int*   sC = (const int*)  d_in[2];
    const float* w1 = (const float*)d_in[3];
    const float* b1 = (const float*)d_in[4];
    const float* w2 = (const float*)d_in[5];
    const float* b2 = (const float*)d_in[6];
    float* out = (float*)d_out;

    char* ws = (char*)d_ws;
    bf16* featsB = (bf16*)ws;                      size_t off = (size_t)MM * DINX * 2;   // 16 MB
    bf16* w1x = (bf16*)(ws + off);                 off += (size_t)DOUT * DINX * 2;       // 1 MB
    bf16* w2b = (bf16*)(ws + off);                 off += (size_t)DOUT * DOUT * 2;       // 0.5 MB
    bf16* hB  = (bf16*)(ws + off);                 off += (size_t)MM * DOUT * 2;         // 8 MB
    float* A1 = (float*)(ws + off);                off += DOUT * 4;
    float* C1 = (float*)(ws + off);

    prep<<<896, 256, 0, stream>>>(w1, b1, w2, w1x, w2b, A1, C1);
    gather_feats<<<MM / 4, 256, 0, stream>>>(x, sL, sC, featsB);

    // GEMM1: h = silu(feats @ w1x^T + sL*A1 + C1)   [8192 x 512] bf16
    gemm_db<true><<<dim3(MM / 64, DOUT / 64), 256, 0, stream>>>(
        featsB, w1x, A1, C1, sL, hB, DOUT, DINX);

    // GEMM2: out = h @ w2^T + b2                    [8192 x 512] fp32
    gemm_db<false><<<dim3(MM / 64, DOUT / 64), 256, 0, stream>>>(
        hB, w2b, b2, nullptr, nullptr, out, DOUT, DOUT);
}

// Round 5
// 129.018 us; speedup vs baseline: 1.1536x; 1.0401x over previous
//
#include <hip/hip_runtime.h>
#include <hip/hip_bf16.h>
#include <stdint.h>

// Problem constants
#define LL   4096
#define CCH  64
#define DOUT 512
#define MM   8192            // B*NP patch-rows
#define TT   0.001f          // 1/FS

using bf16 = __hip_bfloat16;
typedef __attribute__((ext_vector_type(8))) short bf16x8;
typedef __attribute__((ext_vector_type(4))) float f32x4;

__device__ __forceinline__ void async_copy16(void* lds, const void* g) {
    __builtin_amdgcn_global_load_lds(
        (const __attribute__((address_space(1))) void*)g,
        (__attribute__((address_space(3))) void*)lds,
        16, 0, 0);
}

__device__ __forceinline__ uint2 pack4_bf16(float a, float b, float c, float d) {
    union { bf16 h[4]; uint2 u; } p;
    p.h[0] = __float2bfloat16(a);
    p.h[1] = __float2bfloat16(b);
    p.h[2] = __float2bfloat16(c);
    p.h[3] = __float2bfloat16(d);
    return p.u;
}

// ---------------------------------------------------------------------------
// prep: repack weights into [chunk][col][64k] bf16 with XOR-8 swizzle on the
// 16B k-units (unit u = (k>>3) ^ (col&7)) so that (a) each 64KB chunk is one
// contiguous global_load_lds copy and (b) b128 frag reads are conflict-free.
//   blocks [0,512):   w1p[it][col][kk] = w1[col][(it*4+(kk>>4))*32 + (kk&15)]
//   blocks [512,768): w2p[it2][col][kk] = w2[col][it2*64 + kk]
//   blocks [768,896): A1[o] = T*sum_l Wt[o][l]; C1[o] = b1[o]+T*sum_l l*Wt
//                     Wt[o][l] = sum_{j<16} w1[o][l*32+16+j]      (1 wave/o)
// ---------------------------------------------------------------------------
__global__ __launch_bounds__(256) void prep(
    const float* __restrict__ w1, const float* __restrict__ b1,
    const float* __restrict__ w2,
    bf16* __restrict__ w1p, bf16* __restrict__ w2p,
    float* __restrict__ A1, float* __restrict__ C1)
{
    const int blk = blockIdx.x;
    if (blk < 512) {
        int g   = blk * 256 + threadIdx.x;          // 0..131071
        int kk0 = (g & 15) * 4;                     // 0,4,..,60
        int col = (g >> 4) & 511;
        int it  = g >> 13;                          // 0..15
        float4 v = *(const float4*)(w1 + (size_t)col * 2048
                                    + (it * 4 + (kk0 >> 4)) * 32 + (kk0 & 15));
        int off = (it * 512 + col) * 64 + (((kk0 >> 3) ^ (col & 7)) * 8) + (kk0 & 7);
        *(uint2*)(w1p + off) = pack4_bf16(v.x, v.y, v.z, v.w);
    } else if (blk < 768) {
        int g   = (blk - 512) * 256 + threadIdx.x;  // 0..65535
        int kk0 = (g & 15) * 4;
        int col = (g >> 4) & 511;
        int it2 = g >> 13;                          // 0..7
        float4 v = *(const float4*)(w2 + (size_t)col * 512 + it2 * 64 + kk0);
        int off = (it2 * 512 + col) * 64 + (((kk0 >> 3) ^ (col & 7)) * 8) + (kk0 & 7);
        *(uint2*)(w2p + off) = pack4_bf16(v.x, v.y, v.z, v.w);
    } else {
        const int o = (blk - 768) * 4 + (threadIdx.x >> 6);
        const int l = threadIdx.x & 63;
        const float* wr = w1 + (size_t)o * 2048 + l * 32 + 16;
        float s0 = 0.f;
#pragma unroll
        for (int j = 0; j < 16; ++j) s0 += wr[j];
        float s1 = (float)l * s0;
#pragma unroll
        for (int off = 32; off > 0; off >>= 1) {
            s0 += __shfl_down(s0, off);
            s1 += __shfl_down(s1, off);
        }
        if (l == 0) {
            A1[o] = TT * s0;
            C1[o] = b1[o] + TT * s1;
        }
    }
}

// ---------------------------------------------------------------------------
// Megakernel: block = 32 patches x all 512 outputs, both layers fused.
// Phase A: acc = feats(32x1024 gathered from x) @ w1^T  -> silu(+affine) -> Hs
// Phase B: out = Hs(32x512) @ w2^T + b2
// LDS (136 KB): Bs0 64K | Bs1 64K (reused: Hs 32K) | As0 4K | As1 4K
// All tiles stored with the XOR-8 unit swizzle => b128 reads 2-way max.
// ---------------------------------------------------------------------------
__global__ __launch_bounds__(512, 2) void mega(
    const float* __restrict__ x, const int* __restrict__ sLg,
    const int* __restrict__ sCg, const bf16* __restrict__ w1p,
    const bf16* __restrict__ w2p, const float* __restrict__ A1,
    const float* __restrict__ C1, const float* __restrict__ b2,
    float* __restrict__ out)
{
    __shared__ __align__(16) char smem_raw[139264];
    bf16* const Bs0 = (bf16*)smem_raw;
    bf16* const Bs1 = (bf16*)(smem_raw + 65536);
    bf16* const As0 = (bf16*)(smem_raw + 131072);
    bf16* const As1 = (bf16*)(smem_raw + 135168);
    bf16* const Hs  = (bf16*)(smem_raw + 65536);   // overlays Bs1 after phase A

    const int t    = threadIdx.x;
    const int lane = t & 63;
    const int wave = t >> 6;            // 0..7, owns cols [wave*64, wave*64+64)
    const int fr   = lane & 15;
    const int fq   = lane >> 4;
    const int m0   = blockIdx.x * 32;
    const int b    = m0 >> 8;           // 32 rows lie within one batch

    // --- gather mapping: thread -> (row gr, k-seg gs); 4 bf16 per iter
    const int gr  = t >> 4;             // 0..31
    const int gs  = t & 15;
    const int gsl = sLg[m0 + gr];
    const int gsc = sCg[m0 + gr];
    const float* gx = x + ((size_t)b * LL + gsl + (gs >> 2)) * CCH + gsc + (gs & 3) * 4;
    const int aoff = gr * 64 + (((gs >> 1) ^ (gr & 7)) * 8) + (gs & 1) * 4;

    // --- B staging: thread t copies 16B units u = c*512 + t (c=0..7)
    const bf16* bsrc1 = w1p + (size_t)t * 8;
    const bf16* bsrc2 = w2p + (size_t)t * 8;
    const int   wu8   = wave * 64 * 8;   // wave-uniform LDS elem base

    f32x4 acc[2][4] = {};

    // Preamble: stage B(0), write A(0), prefetch x for it=1
    {
#pragma unroll
        for (int c = 0; c < 8; ++c)
            async_copy16(Bs0 + c * 4096 + wu8, bsrc1 + c * 4096);
        float4 v = *(const float4*)gx;
        *(uint2*)(As0 + aoff) = pack4_bf16(v.x, v.y, v.z, v.w);
    }
    float4 xv = *(const float4*)(gx + 4 * CCH);

    // ---- Phase A: 16 iters of BK=64 over K=1024
    for (int it = 0; it < 16; ++it) {
        __syncthreads();   // B(it) staged, A(it) written, reads(it-1) done
        bf16* const Bc = (it & 1) ? Bs1 : Bs0;
        bf16* const Ac = (it & 1) ? As1 : As0;
        if (it < 15) {
            bf16* const Bn = (it & 1) ? Bs0 : Bs1;
            bf16* const An = (it & 1) ? As0 : As1;
            const bf16* bs = bsrc1 + (size_t)(it + 1) * 32768;
#pragma unroll
            for (int c = 0; c < 8; ++c)
                async_copy16(Bn + c * 4096 + wu8, bs + c * 4096);
            *(uint2*)(An + aoff) = pack4_bf16(xv.x, xv.y, xv.z, xv.w);
            const int itn = (it + 2 < 16) ? (it + 2) : 15;
            xv = *(const float4*)(gx + (size_t)itn * 4 * CCH);
        }

        bf16x8 af[2][2], bfr[4][2];
#pragma unroll
        for (int i = 0; i < 2; ++i)
#pragma unroll
            for (int ks = 0; ks < 2; ++ks)
                af[i][ks] = *(const bf16x8*)&Ac[(i * 16 + fr) * 64
                                + (((ks * 4 + fq) ^ (fr & 7)) * 8)];
#pragma unroll
        for (int j = 0; j < 4; ++j)
#pragma unroll
            for (int ks = 0; ks < 2; ++ks)
                bfr[j][ks] = *(const bf16x8*)&Bc[(wave * 64 + j * 16 + fr) * 64
                                + (((ks * 4 + fq) ^ (fr & 7)) * 8)];
#pragma unroll
        for (int ks = 0; ks < 2; ++ks)
#pragma unroll
            for (int i = 0; i < 2; ++i)
#pragma unroll
                for (int j = 0; j < 4; ++j)
                    acc[i][j] = __builtin_amdgcn_mfma_f32_16x16x32_bf16(
                        af[i][ks], bfr[j][ks], acc[i][j], 0, 0, 0);
    }
    __syncthreads();       // all phase-A LDS reads done (Bs1 -> reusable as Hs)

    // Stage w2 chunk 0 while writing h
#pragma unroll
    for (int c = 0; c < 8; ++c)
        async_copy16(Bs0 + c * 4096 + wu8, bsrc2 + c * 4096);

    // ---- Phase A epilogue: silu(acc + sL*A1 + C1) -> Hs (swizzled)
    {
        float slr[2][4];
#pragma unroll
        for (int i = 0; i < 2; ++i)
#pragma unroll
            for (int rr = 0; rr < 4; ++rr)
                slr[i][rr] = (float)sLg[m0 + i * 16 + fq * 4 + rr];
#pragma unroll
        for (int j = 0; j < 4; ++j) {
            const int col = wave * 64 + j * 16 + fr;
            const float av = A1[col];
            const float cv = C1[col];
            const int c8 = col >> 3, c7 = col & 7;
#pragma unroll
            for (int i = 0; i < 2; ++i)
#pragma unroll
                for (int rr = 0; rr < 4; ++rr) {
                    const int row = i * 16 + fq * 4 + rr;
                    float v = acc[i][j][rr] + slr[i][rr] * av + cv;
                    v = v / (1.0f + __expf(-v));
                    Hs[row * 512 + ((c8 ^ (row & 7)) * 8) + c7] = __float2bfloat16(v);
                }
        }
    }

    // ---- Phase B: 8 iters of BK=64 over K=512 (w2 single-buffered in Bs0)
    f32x4 acc2[2][4] = {};
    for (int it2 = 0; it2 < 8; ++it2) {
        __syncthreads();   // w2(it2) staged (+ Hs writes for it2=0)
        bf16x8 af[2][2], bfr[4][2];
#pragma unroll
        for (int i = 0; i < 2; ++i)
#pragma unroll
            for (int ks = 0; ks < 2; ++ks) {
                const int row = i * 16 + fr;
                af[i][ks] = *(const bf16x8*)&Hs[row * 512
                                + (((it2 * 8 + ks * 4 + fq) ^ (row & 7)) * 8)];
            }
#pragma unroll
        for (int j = 0; j < 4; ++j)
#pragma unroll
            for (int ks = 0; ks < 2; ++ks)
                bfr[j][ks] = *(const bf16x8*)&Bs0[(wave * 64 + j * 16 + fr) * 64
                                + (((ks * 4 + fq) ^ (fr & 7)) * 8)];
        __syncthreads();   // all waves' reads of chunk it2 done
        if (it2 < 7) {
            const bf16* bs = bsrc2 + (size_t)(it2 + 1) * 32768;
#pragma unroll
            for (int c = 0; c < 8; ++c)
                async_copy16(Bs0 + c * 4096 + wu8, bs + c * 4096);
        }
#pragma unroll
        for (int ks = 0; ks < 2; ++ks)
#pragma unroll
            for (int i = 0; i < 2; ++i)
#pragma unroll
                for (int j = 0; j < 4; ++j)
                    acc2[i][j] = __builtin_amdgcn_mfma_f32_16x16x32_bf16(
                        af[i][ks], bfr[j][ks], acc2[i][j], 0, 0, 0);
    }

    // ---- Phase B epilogue: + b2, fp32 out, coalesced
#pragma unroll
    for (int j = 0; j < 4; ++j) {
        const int col = wave * 64 + j * 16 + fr;
        const float bv = b2[col];
#pragma unroll
        for (int i = 0; i < 2; ++i)
#pragma unroll
            for (int rr = 0; rr < 4; ++rr) {
                const int row = m0 + i * 16 + fq * 4 + rr;
                out[(size_t)row * 512 + col] = acc2[i][j][rr] + bv;
            }
    }
}

// ---------------------------------------------------------------------------
extern "C" void kernel_launch(void* const* d_in, const int* in_sizes, int n_in,
                              void* d_out, int out_size, void* d_ws, size_t ws_size,
                              hipStream_t stream)
{
    const float* x  = (const float*)d_in[0];
    const int*   sL = (const int*)  d_in[1];
    const int*   sC = (const int*)  d_in[2];
    const float* w1 = (const float*)d_in[3];
    const float* b1 = (const float*)d_in[4];
    const float* w2 = (const float*)d_in[5];
    const float* b2 = (const float*)d_in[6];
    float* out = (float*)d_out;

    char* ws = (char*)d_ws;
    bf16*  w1p = (bf16*)ws;                         // 512*1024*2 = 1 MB
    bf16*  w2p = (bf16*)(ws + (1 << 20));           // 512*512*2  = 0.5 MB
    float* A1  = (float*)(ws + (1 << 20) + (1 << 19));
    float* C1  = A1 + DOUT;

    prep<<<896, 256, 0, stream>>>(w1, b1, w2, w1p, w2p, A1, C1);
    mega<<<MM / 32, 512, 0, stream>>>(x, sL, sC, w1p, w2p, A1, C1, b2, out);
}

// Round 6
// 127.768 us; speedup vs baseline: 1.1649x; 1.0098x over previous
//
#include <hip/hip_runtime.h>
#include <hip/hip_bf16.h>
#include <stdint.h>

// Problem constants
#define LL   4096
#define CCH  64
#define DOUT 512
#define MM   8192            // B*NP patch-rows
#define TT   0.001f          // 1/FS

using bf16 = __hip_bfloat16;
typedef __attribute__((ext_vector_type(8))) short bf16x8;
typedef __attribute__((ext_vector_type(4))) float f32x4;

__device__ __forceinline__ void async_copy16(void* lds, const void* g) {
    __builtin_amdgcn_global_load_lds(
        (const __attribute__((address_space(1))) void*)g,
        (__attribute__((address_space(3))) void*)lds,
        16, 0, 0);
}

__device__ __forceinline__ uint2 pack4_bf16(float a, float b, float c, float d) {
    union { bf16 h[4]; uint2 u; } p;
    p.h[0] = __float2bfloat16(a);
    p.h[1] = __float2bfloat16(b);
    p.h[2] = __float2bfloat16(c);
    p.h[3] = __float2bfloat16(d);
    return p.u;
}

// ---------------------------------------------------------------------------
// prep: repack weights into [chunk][col][64k] bf16 with XOR-8 swizzle on the
// 16B k-units (unit u = (k>>3) ^ (col&7)):
//   blocks [0,512):   w1p[it][col][kk] = w1[col][(it*4+(kk>>4))*32 + (kk&15)]
//   blocks [512,768): w2p[it2][col][kk] = w2[col][it2*64 + kk]
//   blocks [768,896): A1[o] = T*sum_l Wt[o][l]; C1[o] = b1[o]+T*sum_l l*Wt
//                     Wt[o][l] = sum_{j<16} w1[o][l*32+16+j]      (1 wave/o)
// ---------------------------------------------------------------------------
__global__ __launch_bounds__(256) void prep(
    const float* __restrict__ w1, const float* __restrict__ b1,
    const float* __restrict__ w2,
    bf16* __restrict__ w1p, bf16* __restrict__ w2p,
    float* __restrict__ A1, float* __restrict__ C1)
{
    const int blk = blockIdx.x;
    if (blk < 512) {
        int g   = blk * 256 + threadIdx.x;          // 0..131071
        int kk0 = (g & 15) * 4;                     // 0,4,..,60
        int col = (g >> 4) & 511;
        int it  = g >> 13;                          // 0..15
        float4 v = *(const float4*)(w1 + (size_t)col * 2048
                                    + (it * 4 + (kk0 >> 4)) * 32 + (kk0 & 15));
        int off = (it * 512 + col) * 64 + (((kk0 >> 3) ^ (col & 7)) * 8) + (kk0 & 7);
        *(uint2*)(w1p + off) = pack4_bf16(v.x, v.y, v.z, v.w);
    } else if (blk < 768) {
        int g   = (blk - 512) * 256 + threadIdx.x;  // 0..65535
        int kk0 = (g & 15) * 4;
        int col = (g >> 4) & 511;
        int it2 = g >> 13;                          // 0..7
        float4 v = *(const float4*)(w2 + (size_t)col * 512 + it2 * 64 + kk0);
        int off = (it2 * 512 + col) * 64 + (((kk0 >> 3) ^ (col & 7)) * 8) + (kk0 & 7);
        *(uint2*)(w2p + off) = pack4_bf16(v.x, v.y, v.z, v.w);
    } else {
        const int o = (blk - 768) * 4 + (threadIdx.x >> 6);
        const int l = threadIdx.x & 63;
        const float* wr = w1 + (size_t)o * 2048 + l * 32 + 16;
        float s0 = 0.f;
#pragma unroll
        for (int j = 0; j < 16; ++j) s0 += wr[j];
        float s1 = (float)l * s0;
#pragma unroll
        for (int off = 32; off > 0; off >>= 1) {
            s0 += __shfl_down(s0, off);
            s1 += __shfl_down(s1, off);
        }
        if (l == 0) {
            A1[o] = TT * s0;
            C1[o] = b1[o] + TT * s1;
        }
    }
}

// ---------------------------------------------------------------------------
// Megakernel v2: block = 32 patches x all 512 outputs, both layers fused.
// Phase A: acc = feats(32x1024) @ w1^T -> silu(+affine) -> Hs (LDS)
// Phase B: out = Hs(32x512) @ w2^T + b2
// v2 change: ALL x-gather loads issued in a prologue and held in registers,
// so the per-iteration barrier drain covers only the w1 chunk DMA (no HBM
// gather latency serialized into every barrier).
// LDS (136 KB): Bs0 64K | Bs1 64K (reused: Hs 32K) | As0 4K | As1 4K
// ---------------------------------------------------------------------------
__global__ __launch_bounds__(512, 2) void mega(
    const float* __restrict__ x, const int* __restrict__ sLg,
    const int* __restrict__ sCg, const bf16* __restrict__ w1p,
    const bf16* __restrict__ w2p, const float* __restrict__ A1,
    const float* __restrict__ C1, const float* __restrict__ b2,
    float* __restrict__ out)
{
    __shared__ __align__(16) char smem_raw[139264];
    bf16* const Bs0 = (bf16*)smem_raw;
    bf16* const Bs1 = (bf16*)(smem_raw + 65536);
    bf16* const As0 = (bf16*)(smem_raw + 131072);
    bf16* const As1 = (bf16*)(smem_raw + 135168);
    bf16* const Hs  = (bf16*)(smem_raw + 65536);   // overlays Bs1 after phase A

    const int t    = threadIdx.x;
    const int lane = t & 63;
    const int wave = t >> 6;            // 0..7, owns cols [wave*64, wave*64+64)
    const int fr   = lane & 15;
    const int fq   = lane >> 4;
    const int m0   = blockIdx.x * 32;
    const int b    = m0 >> 8;           // 32 rows lie within one batch

    // --- gather mapping: thread -> (row gr, k-seg gs)
    const int gr  = t >> 4;             // 0..31
    const int gs  = t & 15;
    const int gsl = sLg[m0 + gr];
    const int gsc = sCg[m0 + gr];
    const float* gx = x + ((size_t)b * LL + gsl + (gs >> 2)) * CCH + gsc + (gs & 3) * 4;
    const int aoff = gr * 64 + (((gs >> 1) ^ (gr & 7)) * 8) + (gs & 1) * 4;

    // --- B staging: thread t copies 16B units u = c*512 + t (c=0..7)
    const bf16* bsrc1 = w1p + (size_t)t * 8;
    const bf16* bsrc2 = w2p + (size_t)t * 8;
    const int   wu8   = wave * 64 * 8;   // wave-uniform LDS elem base

    // ---- Prologue: issue ALL x loads, convert to bf16 packs held in regs
    uint2 axv[16];
#pragma unroll
    for (int it = 0; it < 16; ++it) {
        float4 v = *(const float4*)(gx + (size_t)it * 4 * CCH);
        axv[it] = pack4_bf16(v.x, v.y, v.z, v.w);
    }

    f32x4 acc[2][4] = {};

    // Stage B(0), write A(0)
#pragma unroll
    for (int c = 0; c < 8; ++c)
        async_copy16(Bs0 + c * 4096 + wu8, bsrc1 + c * 4096);
    *(uint2*)(As0 + aoff) = axv[0];

    // ---- Phase A: 16 iters of BK=64 over K=1024 (fully unrolled)
#pragma unroll
    for (int it = 0; it < 16; ++it) {
        __syncthreads();   // B(it) staged, A(it) written, reads(it-1) done
        bf16* const Bc = (it & 1) ? Bs1 : Bs0;
        const bf16* const Ac = (it & 1) ? As1 : As0;
        if (it < 15) {
            bf16* const Bn = (it & 1) ? Bs0 : Bs1;
            bf16* const An = (it & 1) ? As0 : As1;
            const bf16* bs = bsrc1 + (size_t)(it + 1) * 32768;
#pragma unroll
            for (int c = 0; c < 8; ++c)
                async_copy16(Bn + c * 4096 + wu8, bs + c * 4096);
            *(uint2*)(An + aoff) = axv[it + 1];
        }

        bf16x8 af[2][2], bfr[4][2];
#pragma unroll
        for (int i = 0; i < 2; ++i)
#pragma unroll
            for (int ks = 0; ks < 2; ++ks)
                af[i][ks] = *(const bf16x8*)&Ac[(i * 16 + fr) * 64
                                + (((ks * 4 + fq) ^ (fr & 7)) * 8)];
#pragma unroll
        for (int j = 0; j < 4; ++j)
#pragma unroll
            for (int ks = 0; ks < 2; ++ks)
                bfr[j][ks] = *(const bf16x8*)&Bc[(wave * 64 + j * 16 + fr) * 64
                                + (((ks * 4 + fq) ^ (fr & 7)) * 8)];
#pragma unroll
        for (int ks = 0; ks < 2; ++ks)
#pragma unroll
            for (int i = 0; i < 2; ++i)
#pragma unroll
                for (int j = 0; j < 4; ++j)
                    acc[i][j] = __builtin_amdgcn_mfma_f32_16x16x32_bf16(
                        af[i][ks], bfr[j][ks], acc[i][j], 0, 0, 0);
    }
    __syncthreads();       // all phase-A LDS reads done (Bs1 -> reusable as Hs)

    // Stage w2 chunk 0 while writing h
#pragma unroll
    for (int c = 0; c < 8; ++c)
        async_copy16(Bs0 + c * 4096 + wu8, bsrc2 + c * 4096);

    // ---- Phase A epilogue: silu(acc + sL*A1 + C1) -> Hs (swizzled)
    {
        float slr[2][4];
#pragma unroll
        for (int i = 0; i < 2; ++i)
#pragma unroll
            for (int rr = 0; rr < 4; ++rr)
                slr[i][rr] = (float)sLg[m0 + i * 16 + fq * 4 + rr];
#pragma unroll
        for (int j = 0; j < 4; ++j) {
            const int col = wave * 64 + j * 16 + fr;
            const float av = A1[col];
            const float cv = C1[col];
            const int c8 = col >> 3, c7 = col & 7;
#pragma unroll
            for (int i = 0; i < 2; ++i)
#pragma unroll
                for (int rr = 0; rr < 4; ++rr) {
                    const int row = i * 16 + fq * 4 + rr;
                    float v = acc[i][j][rr] + slr[i][rr] * av + cv;
                    v = v / (1.0f + __expf(-v));
                    Hs[row * 512 + ((c8 ^ (row & 7)) * 8) + c7] = __float2bfloat16(v);
                }
        }
    }

    // ---- Phase B: 8 iters of BK=64 over K=512 (w2 single-buffered in Bs0)
    f32x4 acc2[2][4] = {};
#pragma unroll
    for (int it2 = 0; it2 < 8; ++it2) {
        __syncthreads();   // w2(it2) staged (+ Hs writes for it2=0)
        bf16x8 af[2][2], bfr[4][2];
#pragma unroll
        for (int i = 0; i < 2; ++i)
#pragma unroll
            for (int ks = 0; ks < 2; ++ks) {
                const int row = i * 16 + fr;
                af[i][ks] = *(const bf16x8*)&Hs[row * 512
                                + (((it2 * 8 + ks * 4 + fq) ^ (row & 7)) * 8)];
            }
#pragma unroll
        for (int j = 0; j < 4; ++j)
#pragma unroll
            for (int ks = 0; ks < 2; ++ks)
                bfr[j][ks] = *(const bf16x8*)&Bs0[(wave * 64 + j * 16 + fr) * 64
                                + (((ks * 4 + fq) ^ (fr & 7)) * 8)];
        __syncthreads();   // all waves' reads of chunk it2 done
        if (it2 < 7) {
            const bf16* bs = bsrc2 + (size_t)(it2 + 1) * 32768;
#pragma unroll
            for (int c = 0; c < 8; ++c)
                async_copy16(Bs0 + c * 4096 + wu8, bs + c * 4096);
        }
#pragma unroll
        for (int ks = 0; ks < 2; ++ks)
#pragma unroll
            for (int i = 0; i < 2; ++i)
#pragma unroll
                for (int j = 0; j < 4; ++j)
                    acc2[i][j] = __builtin_amdgcn_mfma_f32_16x16x32_bf16(
                        af[i][ks], bfr[j][ks], acc2[i][j], 0, 0, 0);
    }

    // ---- Phase B epilogue: + b2, fp32 out, coalesced
#pragma unroll
    for (int j = 0; j < 4; ++j) {
        const int col = wave * 64 + j * 16 + fr;
        const float bv = b2[col];
#pragma unroll
        for (int i = 0; i < 2; ++i)
#pragma unroll
            for (int rr = 0; rr < 4; ++rr) {
                const int row = m0 + i * 16 + fq * 4 + rr;
                out[(size_t)row * 512 + col] = acc2[i][j][rr] + bv;
            }
    }
}

// ---------------------------------------------------------------------------
extern "C" void kernel_launch(void* const* d_in, const int* in_sizes, int n_in,
                              void* d_out, int out_size, void* d_ws, size_t ws_size,
                              hipStream_t stream)
{
    const float* x  = (const float*)d_in[0];
    const int*   sL = (const int*)  d_in[1];
    const int*   sC = (const int*)  d_in[2];
    const float* w1 = (const float*)d_in[3];
    const float* b1 = (const float*)d_in[4];
    const float* w2 = (const float*)d_in[5];
    const float* b2 = (const float*)d_in[6];
    float* out = (float*)d_out;

    char* ws = (char*)d_ws;
    bf16*  w1p = (bf16*)ws;                         // 512*1024*2 = 1 MB
    bf16*  w2p = (bf16*)(ws + (1 << 20));           // 512*512*2  = 0.5 MB
    float* A1  = (float*)(ws + (1 << 20) + (1 << 19));
    float* C1  = A1 + DOUT;

    prep<<<896, 256, 0, stream>>>(w1, b1, w2, w1p, w2p, A1, C1);
    mega<<<MM / 32, 512, 0, stream>>>(x, sL, sC, w1p, w2p, A1, C1, b2, out);
}

// Round 7
// 123.838 us; speedup vs baseline: 1.2019x; 1.0317x over previous
//
#include <hip/hip_runtime.h>
#include <hip/hip_bf16.h>
#include <stdint.h>

// Problem constants
#define LL   4096
#define CCH  64
#define DOUT 512
#define MM   8192            // B*NP patch-rows
#define TT   0.001f          // 1/FS

using bf16 = __hip_bfloat16;
typedef __attribute__((ext_vector_type(8))) short bf16x8;
typedef __attribute__((ext_vector_type(4))) float f32x4;

__device__ __forceinline__ uint2 pack4_bf16(float a, float b, float c, float d) {
    union { bf16 h[4]; uint2 u; } p;
    p.h[0] = __float2bfloat16(a);
    p.h[1] = __float2bfloat16(b);
    p.h[2] = __float2bfloat16(c);
    p.h[3] = __float2bfloat16(d);
    return p.u;
}

// ---------------------------------------------------------------------------
// prep: repack weights PLAIN (no swizzle) into k-chunked layout so a wave's
// B-fragment global load is one contiguous 1 KB block:
//   w1g[ic][col][kk]  (ic=0..31, kk=0..31): = w1[col][l*32+j], k=ic*32+kk,
//                      l=k>>4, j=k&15   (x-part columns only)
//   w2g[ic2][col][kk] (ic2=0..15):        = w2[col][ic2*32+kk]
//   blocks [768,896): A1[o] = T*sum_l Wt[o][l]; C1[o] = b1[o]+T*sum_l l*Wt
//                     Wt[o][l] = sum_{j<16} w1[o][l*32+16+j]      (1 wave/o)
// ---------------------------------------------------------------------------
__global__ __launch_bounds__(256) void prep(
    const float* __restrict__ w1, const float* __restrict__ b1,
    const float* __restrict__ w2,
    bf16* __restrict__ w1g, bf16* __restrict__ w2g,
    float* __restrict__ A1, float* __restrict__ C1)
{
    const int blk = blockIdx.x;
    if (blk < 512) {
        int g   = blk * 256 + threadIdx.x;          // 0..131071, 4 elems each
        int kk0 = (g & 7) * 4;                      // 0,4,..,28
        int col = (g >> 3) & 511;
        int ic  = g >> 12;                          // 0..31
        int l   = ic * 2 + (kk0 >> 4);
        int j0  = kk0 & 15;
        float4 v = *(const float4*)(w1 + (size_t)col * 2048 + l * 32 + j0);
        *(uint2*)(w1g + ((size_t)(ic * 512 + col) * 32 + kk0)) =
            pack4_bf16(v.x, v.y, v.z, v.w);
    } else if (blk < 768) {
        int g   = (blk - 512) * 256 + threadIdx.x;  // 0..65535
        int kk0 = (g & 7) * 4;
        int col = (g >> 3) & 511;
        int ic2 = g >> 12;                          // 0..15
        float4 v = *(const float4*)(w2 + (size_t)col * 512 + ic2 * 32 + kk0);
        *(uint2*)(w2g + ((size_t)(ic2 * 512 + col) * 32 + kk0)) =
            pack4_bf16(v.x, v.y, v.z, v.w);
    } else {
        const int o = (blk - 768) * 4 + (threadIdx.x >> 6);
        const int l = threadIdx.x & 63;
        const float* wr = w1 + (size_t)o * 2048 + l * 32 + 16;
        float s0 = 0.f;
#pragma unroll
        for (int j = 0; j < 16; ++j) s0 += wr[j];
        float s1 = (float)l * s0;
#pragma unroll
        for (int off = 32; off > 0; off >>= 1) {
            s0 += __shfl_down(s0, off);
            s1 += __shfl_down(s1, off);
        }
        if (l == 0) {
            A1[o] = TT * s0;
            C1[o] = b1[o] + TT * s1;
        }
    }
}

// ---------------------------------------------------------------------------
// Megakernel v3: block = 32 patches x 512 outputs, both layers fused.
// - Prologue: gather x -> bf16 A-tile (32x1024, XOR-8 swizzled) in LDS, once.
// - Phase A (32 iters, NO barriers): B-frags global->VGPR (pipelined),
//   A-frags from LDS, 8 MFMAs/wave/iter.
// - Hs (32x512) overlays the A region; phase B identical structure vs w2g.
// Only 3 __syncthreads in the whole kernel. LDS = 64 KB.
// ---------------------------------------------------------------------------
__global__ __launch_bounds__(512, 2) void mega(
    const float* __restrict__ x, const int* __restrict__ sLg,
    const int* __restrict__ sCg, const bf16* __restrict__ w1g,
    const bf16* __restrict__ w2g, const float* __restrict__ A1,
    const float* __restrict__ C1, const float* __restrict__ b2,
    float* __restrict__ out)
{
    __shared__ __align__(16) bf16 Asm[32 * 1024];   // 64 KB; Hs overlays later
    bf16* const Hs = Asm;                           // 32 x 512 after phase A

    const int t    = threadIdx.x;
    const int lane = t & 63;
    const int wave = t >> 6;            // 0..7, owns cols [wave*64, wave*64+64)
    const int fr   = lane & 15;
    const int fq   = lane >> 4;
    const int m0   = blockIdx.x * 32;
    const int b    = m0 >> 8;           // 32 rows lie within one batch

    // ---- Prologue: gather x into swizzled A-tile (one shot)
    {
        const int gr  = t >> 4;         // patch row 0..31
        const int gs  = t & 15;
        const int gsl = sLg[m0 + gr];
        const int gsc = sCg[m0 + gr];
        const float* gx = x + ((size_t)b * LL + gsl + (gs >> 2)) * CCH
                            + gsc + (gs & 3) * 4;
        float4 xv[16];
#pragma unroll
        for (int p = 0; p < 16; ++p)
            xv[p] = *(const float4*)(gx + (size_t)p * 4 * CCH);
#pragma unroll
        for (int p = 0; p < 16; ++p) {
            const int l = 4 * p + (gs >> 2);
            const int u = l * 2 + ((gs & 3) >> 1);          // k-unit = (l*16+j)>>3
            const int idx = gr * 1024 + ((u ^ (gr & 7)) * 8) + (gs & 1) * 4;
            *(uint2*)(Asm + idx) = pack4_bf16(xv[p].x, xv[p].y, xv[p].z, xv[p].w);
        }
    }
    __syncthreads();                    // A-tile ready

    // ---- Phase A: 32 iters of k=32, B-frags direct from global (pipelined)
    const bf16* const w1base = w1g + (size_t)(wave * 64 + fr) * 32 + fq * 8;
    f32x4 acc[2][4] = {};
    {
        bf16x8 bnx[4];
#pragma unroll
        for (int j = 0; j < 4; ++j)
            bnx[j] = *(const bf16x8*)(w1base + j * 512);
#pragma unroll
        for (int it = 0; it < 32; ++it) {
            bf16x8 bcur[4];
#pragma unroll
            for (int j = 0; j < 4; ++j) bcur[j] = bnx[j];
            if (it < 31) {
                const bf16* p = w1base + (size_t)(it + 1) * 16384;
#pragma unroll
                for (int j = 0; j < 4; ++j)
                    bnx[j] = *(const bf16x8*)(p + j * 512);
            }
            bf16x8 af[2];
#pragma unroll
            for (int i = 0; i < 2; ++i) {
                const int row = i * 16 + fr;
                const int u   = it * 4 + fq;
                af[i] = *(const bf16x8*)&Asm[row * 1024 + ((u ^ (row & 7)) * 8)];
            }
#pragma unroll
            for (int i = 0; i < 2; ++i)
#pragma unroll
                for (int j = 0; j < 4; ++j)
                    acc[i][j] = __builtin_amdgcn_mfma_f32_16x16x32_bf16(
                        af[i], bcur[j], acc[i][j], 0, 0, 0);
        }
    }
    __syncthreads();                    // all A-frag reads done (Asm -> Hs)

    // ---- Phase A epilogue: silu(acc + sL*A1 + C1) -> Hs (swizzled)
    {
        float slr[2][4];
#pragma unroll
        for (int i = 0; i < 2; ++i)
#pragma unroll
            for (int rr = 0; rr < 4; ++rr)
                slr[i][rr] = (float)sLg[m0 + i * 16 + fq * 4 + rr];
#pragma unroll
        for (int j = 0; j < 4; ++j) {
            const int col = wave * 64 + j * 16 + fr;
            const float av = A1[col];
            const float cv = C1[col];
            const int c8 = col >> 3, c7 = col & 7;
#pragma unroll
            for (int i = 0; i < 2; ++i)
#pragma unroll
                for (int rr = 0; rr < 4; ++rr) {
                    const int row = i * 16 + fq * 4 + rr;
                    float v = acc[i][j][rr] + slr[i][rr] * av + cv;
                    v = v / (1.0f + __expf(-v));
                    Hs[row * 512 + ((c8 ^ (row & 7)) * 8) + c7] = __float2bfloat16(v);
                }
        }
    }
    __syncthreads();                    // Hs ready

    // ---- Phase B: 16 iters of k=32, w2-frags direct from global (pipelined)
    const bf16* const w2base = w2g + (size_t)(wave * 64 + fr) * 32 + fq * 8;
    f32x4 acc2[2][4] = {};
    {
        bf16x8 bnx[4];
#pragma unroll
        for (int j = 0; j < 4; ++j)
            bnx[j] = *(const bf16x8*)(w2base + j * 512);
#pragma unroll
        for (int it2 = 0; it2 < 16; ++it2) {
            bf16x8 bcur[4];
#pragma unroll
            for (int j = 0; j < 4; ++j) bcur[j] = bnx[j];
            if (it2 < 15) {
                const bf16* p = w2base + (size_t)(it2 + 1) * 16384;
#pragma unroll
                for (int j = 0; j < 4; ++j)
                    bnx[j] = *(const bf16x8*)(p + j * 512);
            }
            bf16x8 af[2];
#pragma unroll
            for (int i = 0; i < 2; ++i) {
                const int row = i * 16 + fr;
                const int u2  = it2 * 4 + fq;
                af[i] = *(const bf16x8*)&Hs[row * 512 + ((u2 ^ (row & 7)) * 8)];
            }
#pragma unroll
            for (int i = 0; i < 2; ++i)
#pragma unroll
                for (int j = 0; j < 4; ++j)
                    acc2[i][j] = __builtin_amdgcn_mfma_f32_16x16x32_bf16(
                        af[i], bcur[j], acc2[i][j], 0, 0, 0);
        }
    }

    // ---- Phase B epilogue: + b2, fp32 out, coalesced
#pragma unroll
    for (int j = 0; j < 4; ++j) {
        const int col = wave * 64 + j * 16 + fr;
        const float bv = b2[col];
#pragma unroll
        for (int i = 0; i < 2; ++i)
#pragma unroll
            for (int rr = 0; rr < 4; ++rr) {
                const int row = m0 + i * 16 + fq * 4 + rr;
                out[(size_t)row * 512 + col] = acc2[i][j][rr] + bv;
            }
    }
}

// ---------------------------------------------------------------------------
extern "C" void kernel_launch(void* const* d_in, const int* in_sizes, int n_in,
                              void* d_out, int out_size, void* d_ws, size_t ws_size,
                              hipStream_t stream)
{
    const float* x  = (const float*)d_in[0];
    const int*   sL = (const int*)  d_in[1];
    const int*   sC = (const int*)  d_in[2];
    const float* w1 = (const float*)d_in[3];
    const float* b1 = (const float*)d_in[4];
    const float* w2 = (const float*)d_in[5];
    const float* b2 = (const float*)d_in[6];
    float* out = (float*)d_out;

    char* ws = (char*)d_ws;
    bf16*  w1g = (bf16*)ws;                         // 512*1024*2 = 1 MB
    bf16*  w2g = (bf16*)(ws + (1 << 20));           // 512*512*2  = 0.5 MB
    float* A1  = (float*)(ws + (1 << 20) + (1 << 19));
    float* C1  = A1 + DOUT;

    prep<<<896, 256, 0, stream>>>(w1, b1, w2, w1g, w2g, A1, C1);
    mega<<<MM / 32, 512, 0, stream>>>(x, sL, sC, w1g, w2g, A1, C1, b2, out);
}